// Round 4
// baseline (885.842 us; speedup 1.0000x reference)
//
#include <hip/hip_runtime.h>
#include <math.h>

#define N_NODES 100000
#define N_EDGES 3200000
#define NX 8           // XCD count (private copies)
#define D 64
#define D4 16
#define EPS 1e-16f
#define SPILL_MAX 262144

__device__ __forceinline__ int xcc_id() {
    unsigned v;
    asm volatile("s_getreg_b32 %0, hwreg(HW_REG_XCC_ID)" : "=s"(v));
    return (int)(v & (NX - 1));
}

__device__ __forceinline__ unsigned short f_to_bf(float f) {
    unsigned u = __float_as_uint(f);
    unsigned r = (u + 0x7FFFu + ((u >> 16) & 1u)) >> 16;  // RNE
    return (unsigned short)r;
}
__device__ __forceinline__ float bf_to_f(unsigned short b) {
    return __uint_as_float((unsigned)b << 16);
}
__device__ __forceinline__ float4 bf4_to_f4(ushort4 u) {
    return make_float4(bf_to_f(u.x), bf_to_f(u.y), bf_to_f(u.z), bf_to_f(u.w));
}

// CAS-add of two floats into a packed bf16 pair (spill path only; rare)
__device__ void bf16pair_atomic_add(unsigned* w, float a0, float a1) {
    unsigned old = __hip_atomic_load(w, __ATOMIC_RELAXED, __HIP_MEMORY_SCOPE_AGENT);
    while (true) {
        float lo = __uint_as_float((old & 0xFFFFu) << 16) + a0;
        float hi = __uint_as_float(old & 0xFFFF0000u) + a1;
        unsigned nv = (unsigned)f_to_bf(lo) | ((unsigned)f_to_bf(hi) << 16);
        unsigned prev = atomicCAS(w, old, nv);
        if (prev == old) break;
        old = prev;
    }
}

// Single edge pass. Per edge: 2 XCD-private workgroup-scope atomics (L2-local)
// + 1 random 8B slot store. Only the store should hit the fabric.
__global__ void scatter_build(const int* __restrict__ ei, const float* __restrict__ attr,
                              unsigned* __restrict__ pos8, float* __restrict__ s_from8,
                              float* __restrict__ s_extra,
                              uint2* __restrict__ slots, int subcap, int cap,
                              unsigned* __restrict__ spill_cnt, int3* __restrict__ spill) {
    int e = blockIdx.x * blockDim.x + threadIdx.x;
    if (e >= N_EDGES) return;
    int x = xcc_id();
    int f = ei[e];
    int t = ei[N_EDGES + e];
    float ex = __expf(attr[e]);
    __hip_atomic_fetch_add(&s_from8[(size_t)x * N_NODES + f], ex,
                           __ATOMIC_RELAXED, __HIP_MEMORY_SCOPE_WORKGROUP);
    unsigned c = __hip_atomic_fetch_add(&pos8[(size_t)x * N_NODES + t], 1u,
                                        __ATOMIC_RELAXED, __HIP_MEMORY_SCOPE_WORKGROUP);
    if (c < (unsigned)subcap) {
        slots[(size_t)t * cap + x * subcap + c] = make_uint2((unsigned)f, __float_as_uint(ex));
    } else {
        unsafeAtomicAdd(&s_extra[t], ex);
        unsigned si = atomicAdd(spill_cnt, 1u);
        if (si < SPILL_MAX) spill[si] = make_int3(t, f, (int)__float_as_uint(ex));
    }
}

// s_from_inv[f] = rsqrt(sum over 8 copies + EPS)
__global__ void reduce_sfrom(const float* __restrict__ s_from8, float* __restrict__ s_from_inv) {
    int i = blockIdx.x * blockDim.x + threadIdx.x;
    if (i >= N_NODES) return;
    float s = 0.f;
    #pragma unroll
    for (int x = 0; x < NX; ++x) s += s_from8[(size_t)x * N_NODES + i];
    s_from_inv[i] = rsqrtf(s + EPS);
}

// Layer 1: f32 emb gather; computes s_to from sub-rows (+s_extra), finalizes
// per-edge w (written back over slot.y), writes bufA (bf16) and acc=emb+l1 (f32).
__global__ void propagate1(const unsigned* __restrict__ pos8, uint2* __restrict__ slots,
                           int subcap, int cap,
                           const float* __restrict__ s_from_inv, const float* __restrict__ s_extra,
                           float* __restrict__ rs_to,
                           const float* __restrict__ emb, ushort4* __restrict__ dst_bf,
                           float* __restrict__ acc) {
    int node = blockIdx.x * 16 + (threadIdx.x >> 4);
    int lane = threadIdx.x & 15;
    if (node >= N_NODES) return;
    unsigned deg[NX];
    #pragma unroll
    for (int x = 0; x < NX; ++x) {
        unsigned d = pos8[(size_t)x * N_NODES + node];
        deg[x] = d < (unsigned)subcap ? d : (unsigned)subcap;
    }
    float s = s_extra[node];
    #pragma unroll
    for (int x = 0; x < NX; ++x) {
        size_t base = (size_t)node * cap + (size_t)x * subcap;
        for (unsigned k = 0; k < deg[x]; ++k) s += __uint_as_float(slots[base + k].y);
    }
    float rs = rsqrtf(s + EPS);
    if (lane == 0) rs_to[node] = rs;
    const float4* __restrict__ emb4 = (const float4*)emb;
    float ax = 0.f, ay = 0.f, az = 0.f, aw = 0.f;
    #pragma unroll
    for (int x = 0; x < NX; ++x) {
        size_t base = (size_t)node * cap + (size_t)x * subcap;
        for (unsigned k = 0; k < deg[x]; ++k) {
            uint2 sl = slots[base + k];               // all 16 lanes read first...
            int f = (int)sl.x;
            float w = __uint_as_float(sl.y) * rs * s_from_inv[f];
            if (lane == 0) ((float*)&slots[base + k])[1] = w;  // ...then lane0 stores w
            float4 v = emb4[(size_t)f * D4 + lane];
            ax = fmaf(w, v.x, ax); ay = fmaf(w, v.y, ay);
            az = fmaf(w, v.z, az); aw = fmaf(w, v.w, aw);
        }
    }
    size_t o = (size_t)node * D4 + lane;
    dst_bf[o] = make_ushort4(f_to_bf(ax), f_to_bf(ay), f_to_bf(az), f_to_bf(aw));
    float4 e0 = emb4[o];
    ((float4*)acc)[o] = make_float4(e0.x + ax, e0.y + ay, e0.z + az, e0.w + aw);
}

// Layers 2-3: bf16 gather with precomputed weights in slot.y
__global__ void propagateN(const unsigned* __restrict__ pos8, const uint2* __restrict__ slots,
                           int subcap, int cap,
                           const ushort4* __restrict__ cur, ushort4* __restrict__ dst_bf,
                           float* __restrict__ acc, int write_dst) {
    int node = blockIdx.x * 16 + (threadIdx.x >> 4);
    int lane = threadIdx.x & 15;
    if (node >= N_NODES) return;
    float ax = 0.f, ay = 0.f, az = 0.f, aw = 0.f;
    #pragma unroll
    for (int x = 0; x < NX; ++x) {
        unsigned d = pos8[(size_t)x * N_NODES + node];
        unsigned deg = d < (unsigned)subcap ? d : (unsigned)subcap;
        size_t base = (size_t)node * cap + (size_t)x * subcap;
        for (unsigned k = 0; k < deg; ++k) {
            uint2 sl = slots[base + k];
            int f = (int)sl.x;
            float w = __uint_as_float(sl.y);
            float4 v = bf4_to_f4(cur[(size_t)f * D4 + lane]);
            ax = fmaf(w, v.x, ax); ay = fmaf(w, v.y, ay);
            az = fmaf(w, v.z, az); aw = fmaf(w, v.w, aw);
        }
    }
    size_t o = (size_t)node * D4 + lane;
    if (write_dst) dst_bf[o] = make_ushort4(f_to_bf(ax), f_to_bf(ay), f_to_bf(az), f_to_bf(aw));
    float4 c = ((float4*)acc)[o];
    c.x += ax; c.y += ay; c.z += az; c.w += aw;
    ((float4*)acc)[o] = c;
}

// Exact fixup for spilled edges (normally ~0 entries). cur_bf16 selects gather fmt.
__global__ void spill_pass(const unsigned* __restrict__ spill_cnt, const int3* __restrict__ spill,
                           const float* __restrict__ rs_to, const float* __restrict__ s_from_inv,
                           const void* __restrict__ cur, int cur_bf16,
                           void* __restrict__ dst_bf, float* __restrict__ acc, int write_dst) {
    unsigned n = *spill_cnt;
    if (n > SPILL_MAX) n = SPILL_MAX;
    unsigned total = n * 16;
    for (unsigned i = blockIdx.x * blockDim.x + threadIdx.x; i < total;
         i += gridDim.x * blockDim.x) {
        unsigned e = i >> 4;
        int lane = i & 15;
        int3 sp = spill[e];
        int t = sp.x, f = sp.y;
        float ex = __uint_as_float((unsigned)sp.z);
        float w = ex * rs_to[t] * s_from_inv[f];
        float4 v;
        if (cur_bf16) v = bf4_to_f4(((const ushort4*)cur)[(size_t)f * D4 + lane]);
        else          v = ((const float4*)cur)[(size_t)f * D4 + lane];
        float m0 = w * v.x, m1 = w * v.y, m2 = w * v.z, m3 = w * v.w;
        if (write_dst) {
            unsigned* wp = (unsigned*)dst_bf + ((size_t)t * D4 + lane) * 2;
            bf16pair_atomic_add(wp + 0, m0, m1);
            bf16pair_atomic_add(wp + 1, m2, m3);
        }
        float* ap = acc + ((size_t)t * D4 + lane) * 4;
        unsafeAtomicAdd(ap + 0, m0);
        unsafeAtomicAdd(ap + 1, m1);
        unsafeAtomicAdd(ap + 2, m2);
        unsafeAtomicAdd(ap + 3, m3);
    }
}

// out_emb = emb (region served as bufB until now); acc *= 0.25
__global__ void finalize(const float4* __restrict__ emb4, float4* __restrict__ out_emb4,
                         float4* __restrict__ acc4) {
    int i = blockIdx.x * blockDim.x + threadIdx.x;
    if (i >= N_NODES * D4) return;
    out_emb4[i] = emb4[i];
    float4 v = acc4[i];
    v.x *= 0.25f; v.y *= 0.25f; v.z *= 0.25f; v.w *= 0.25f;
    acc4[i] = v;
}

extern "C" void kernel_launch(void* const* d_in, const int* in_sizes, int n_in,
                              void* d_out, int out_size, void* d_ws, size_t ws_size,
                              hipStream_t stream) {
    const float* emb = (const float*)d_in[0];
    const int* ei = (const int*)d_in[1];
    const float* attr = (const float*)d_in[2];

    float* out_emb = (float*)d_out;          // hosts bufB (bf16) during layers 2-3
    float* out_acc = out_emb + (size_t)N_NODES * D;
    ushort4* bufB = (ushort4*)out_emb;

    char* ws = (char*)d_ws;
    size_t off = 0;
    auto alloc = [&](size_t bytes) -> void* {
        void* p = ws + off;
        off += (bytes + 255) & ~(size_t)255;
        return p;
    };
    unsigned* pos8      = (unsigned*)alloc((size_t)NX * N_NODES * 4);
    float*    s_from8   = (float*)   alloc((size_t)NX * N_NODES * 4);
    float*    s_extra   = (float*)   alloc((size_t)N_NODES * 4);
    unsigned* spill_cnt = (unsigned*)alloc(256);
    size_t zero_bytes = off;
    float*    s_from_inv= (float*)   alloc((size_t)N_NODES * 4);
    float*    rs_to     = (float*)   alloc((size_t)N_NODES * 4);
    int3*     spill     = (int3*)    alloc((size_t)SPILL_MAX * 12);
    ushort4*  bufA      = (ushort4*) alloc((size_t)N_NODES * D * 2);
    size_t remain = (ws_size > off) ? ws_size - off : 0;
    int subcap = (int)(remain / ((size_t)N_NODES * NX * 8));
    if (subcap > 14) subcap = 14;
    if (subcap < 8) subcap = 8;   // spill path keeps exactness if ws is tight
    int cap = subcap * NX;
    uint2* slots = (uint2*)alloc((size_t)N_NODES * cap * 8);

    hipMemsetAsync(d_ws, 0, zero_bytes, stream);

    const int EB = 256;
    const int egrid = (N_EDGES + EB - 1) / EB;
    scatter_build<<<egrid, EB, 0, stream>>>(ei, attr, pos8, s_from8, s_extra,
                                            slots, subcap, cap, spill_cnt, spill);
    reduce_sfrom<<<(N_NODES + 255) / 256, 256, 0, stream>>>(s_from8, s_from_inv);

    const int pgrid = (N_NODES * 16 + 255) / 256;
    propagate1<<<pgrid, 256, 0, stream>>>(pos8, slots, subcap, cap, s_from_inv, s_extra,
                                          rs_to, emb, bufA, out_acc);
    spill_pass<<<64, 256, 0, stream>>>(spill_cnt, spill, rs_to, s_from_inv,
                                       emb, 0, bufA, out_acc, 1);
    propagateN<<<pgrid, 256, 0, stream>>>(pos8, slots, subcap, cap, bufA, bufB, out_acc, 1);
    spill_pass<<<64, 256, 0, stream>>>(spill_cnt, spill, rs_to, s_from_inv,
                                       bufA, 1, bufB, out_acc, 1);
    propagateN<<<pgrid, 256, 0, stream>>>(pos8, slots, subcap, cap, bufB, nullptr, out_acc, 0);
    spill_pass<<<64, 256, 0, stream>>>(spill_cnt, spill, rs_to, s_from_inv,
                                       bufB, 1, nullptr, out_acc, 0);

    const int vgrid = (N_NODES * D4 + 255) / 256;
    finalize<<<vgrid, 256, 0, stream>>>((const float4*)emb, (float4*)out_emb, (float4*)out_acc);
}

// Round 5
// 545.153 us; speedup vs baseline: 1.6249x; 1.6249x over previous
//
#include <hip/hip_runtime.h>
#include <math.h>

#define N_NODES 100000
#define N_EDGES 3200000
#define D4 16
#define EPS 1e-16f
#define BSH 8
#define BNODES 256
#define NBK 391              /* ceil(100000/256) */
#define PE 16
#define PTILE (PE * 256)

static __device__ __forceinline__ unsigned short f_to_bf(float f) {
    unsigned u = __float_as_uint(f);
    unsigned r = (u + 0x7FFFu + ((u >> 16) & 1u)) >> 16;  // RNE
    return (unsigned short)r;
}
static __device__ __forceinline__ float bf_to_f(unsigned short b) {
    return __uint_as_float((unsigned)b << 16);
}
static __device__ __forceinline__ float4 bf4_to_f4(ushort4 u) {
    return make_float4(bf_to_f(u.x), bf_to_f(u.y), bf_to_f(u.z), bf_to_f(u.w));
}

// ---- Phase A: exact bucket histograms (per-block LDS, one flush per block) ----
__global__ void hist_kernel(const int* __restrict__ ei,
                            unsigned* __restrict__ cnt_t, unsigned* __restrict__ cnt_f) {
    __shared__ unsigned ht[NBK], hf[NBK];
    for (int i = threadIdx.x; i < NBK; i += 256) { ht[i] = 0; hf[i] = 0; }
    __syncthreads();
    int stride = gridDim.x * blockDim.x;
    for (int e = blockIdx.x * blockDim.x + threadIdx.x; e < N_EDGES; e += stride) {
        atomicAdd(&hf[((unsigned)ei[e]) >> BSH], 1u);
        atomicAdd(&ht[((unsigned)ei[N_EDGES + e]) >> BSH], 1u);
    }
    __syncthreads();
    for (int i = threadIdx.x; i < NBK; i += 256) {
        if (ht[i]) atomicAdd(&cnt_t[i], ht[i]);
        if (hf[i]) atomicAdd(&cnt_f[i], hf[i]);
    }
}

// ---- Phase B: exclusive scan of bucket counts -> bases + reservation cursors ----
__global__ void scan_buckets(const unsigned* __restrict__ cnt_t, const unsigned* __restrict__ cnt_f,
                             unsigned* __restrict__ base_t, unsigned* __restrict__ base_f,
                             unsigned* __restrict__ pos_t, unsigned* __restrict__ pos_f) {
    __shared__ unsigned sc[512];
    int tid = threadIdx.x;
    unsigned own = (tid < NBK) ? cnt_t[tid] : 0u;
    sc[tid] = own;
    __syncthreads();
    for (int o = 1; o < 512; o <<= 1) {
        unsigned v = (tid >= o) ? sc[tid - o] : 0u;
        __syncthreads();
        sc[tid] += v;
        __syncthreads();
    }
    if (tid < NBK) { unsigned ex = sc[tid] - own; base_t[tid] = ex; pos_t[tid] = ex; }
    if (tid == NBK - 1) base_t[NBK] = sc[tid];
    __syncthreads();
    own = (tid < NBK) ? cnt_f[tid] : 0u;
    sc[tid] = own;
    __syncthreads();
    for (int o = 1; o < 512; o <<= 1) {
        unsigned v = (tid >= o) ? sc[tid - o] : 0u;
        __syncthreads();
        sc[tid] += v;
        __syncthreads();
    }
    if (tid < NBK) { unsigned ex = sc[tid] - own; base_f[tid] = ex; pos_f[tid] = ex; }
    if (tid == NBK - 1) base_f[NBK] = sc[tid];
}

// ---- Phase C: single-pass partition into dst-bucketed and src-bucketed arrays.
// Per block: stage PE edges/thread in regs, LDS hist, one reservation per
// (block,bucket), then write runs. bt word0 = f | (t_local<<17); bf word0 = f_local.
__global__ void partition(const int* __restrict__ ei, const float* __restrict__ attr,
                          unsigned* __restrict__ pos_t, unsigned* __restrict__ pos_f,
                          uint2* __restrict__ bt, uint2* __restrict__ bf) {
    __shared__ unsigned ht[NBK], hf[NBK];
    for (int i = threadIdx.x; i < NBK; i += 256) { ht[i] = 0; hf[i] = 0; }
    __syncthreads();
    const int tile = blockIdx.x * PTILE;
    unsigned fv[PE], tv[PE];
    float xv[PE];
    #pragma unroll
    for (int k = 0; k < PE; ++k) {
        int e = tile + k * 256 + threadIdx.x;
        if (e < N_EDGES) {
            fv[k] = (unsigned)ei[e];
            tv[k] = (unsigned)ei[N_EDGES + e];
            xv[k] = __expf(attr[e]);
            atomicAdd(&ht[tv[k] >> BSH], 1u);
            atomicAdd(&hf[fv[k] >> BSH], 1u);
        } else {
            tv[k] = 0xFFFFFFFFu;
        }
    }
    __syncthreads();
    for (int i = threadIdx.x; i < NBK; i += 256) {
        unsigned c = ht[i];
        if (c) ht[i] = atomicAdd(&pos_t[i], c);
        c = hf[i];
        if (c) hf[i] = atomicAdd(&pos_f[i], c);
    }
    __syncthreads();
    #pragma unroll
    for (int k = 0; k < PE; ++k) {
        if (tv[k] != 0xFFFFFFFFu) {
            unsigned p = atomicAdd(&ht[tv[k] >> BSH], 1u);
            bt[p] = make_uint2(fv[k] | ((tv[k] & 255u) << 17), __float_as_uint(xv[k]));
            unsigned q = atomicAdd(&hf[fv[k] >> BSH], 1u);
            bf[q] = make_uint2(fv[k] & 255u, __float_as_uint(xv[k]));
        }
    }
}

// ---- Phase D: per-src-bucket sums -> s_from_inv (LDS only, no global atomics) ----
__global__ void bucket_sum_f(const unsigned* __restrict__ base_f, const uint2* __restrict__ bf,
                             float* __restrict__ s_from_inv) {
    __shared__ float s[BNODES];
    int b = blockIdx.x, tid = threadIdx.x;
    s[tid] = 0.f;
    __syncthreads();
    unsigned lo = base_f[b], hi = base_f[b + 1];
    for (unsigned i = lo + tid; i < hi; i += 256) {
        uint2 u = bf[i];
        atomicAdd(&s[u.x & 255u], __uint_as_float(u.y));
    }
    __syncthreads();
    int node = b * BNODES + tid;
    if (node < N_NODES) s_from_inv[node] = rsqrtf(s[tid] + EPS);
}

// ---- Phase E: per-dst-bucket: exact dense CSR (row_ptr) + final edge weights ----
__global__ void bucket_csr_t(const unsigned* __restrict__ base_t, const uint2* __restrict__ bt,
                             const float* __restrict__ s_from_inv,
                             unsigned* __restrict__ row_ptr, uint2* __restrict__ slots) {
    __shared__ unsigned cnt[BNODES];
    __shared__ float sto[BNODES];
    __shared__ unsigned sc[BNODES];
    __shared__ float rs[BNODES];
    __shared__ unsigned cur[BNODES];
    int b = blockIdx.x, tid = threadIdx.x;
    cnt[tid] = 0;
    sto[tid] = 0.f;
    __syncthreads();
    unsigned lo = base_t[b], hi = base_t[b + 1];
    for (unsigned i = lo + tid; i < hi; i += 256) {
        uint2 u = bt[i];
        unsigned tl = u.x >> 17;
        atomicAdd(&cnt[tl], 1u);
        atomicAdd(&sto[tl], __uint_as_float(u.y));
    }
    __syncthreads();
    unsigned own = cnt[tid];
    sc[tid] = own;
    __syncthreads();
    for (int o = 1; o < 256; o <<= 1) {
        unsigned v = (tid >= o) ? sc[tid - o] : 0u;
        __syncthreads();
        sc[tid] += v;
        __syncthreads();
    }
    unsigned excl = sc[tid] - own;
    int node = b * BNODES + tid;
    if (node < N_NODES) row_ptr[node] = lo + excl;
    if (b == NBK - 1 && tid == 0) row_ptr[N_NODES] = N_EDGES;
    rs[tid] = rsqrtf(sto[tid] + EPS);
    cur[tid] = lo + excl;
    __syncthreads();
    for (unsigned i = lo + tid; i < hi; i += 256) {
        uint2 u = bt[i];
        unsigned tl = u.x >> 17;
        unsigned f = u.x & 0x1FFFFu;
        float w = __uint_as_float(u.y) * rs[tl] * s_from_inv[f];
        unsigned p = atomicAdd(&cur[tl], 1u);
        slots[p] = make_uint2(f, __float_as_uint(w));
    }
}

// ---- Layer 1: f32 emb gather; writes bufA (bf16) and acc = emb + l1 (f32) ----
__global__ void propagate1(const unsigned* __restrict__ row_ptr, const uint2* __restrict__ slots,
                           const float* __restrict__ emb, ushort4* __restrict__ bufA,
                           float* __restrict__ acc) {
    int node = blockIdx.x * 16 + (threadIdx.x >> 4);
    int lane = threadIdx.x & 15;
    if (node >= N_NODES) return;
    unsigned beg = row_ptr[node], end = row_ptr[node + 1];
    const float4* __restrict__ emb4 = (const float4*)emb;
    float ax = 0.f, ay = 0.f, az = 0.f, aw = 0.f;
    for (unsigned k = beg; k < end; ++k) {
        uint2 sl = slots[k];
        float w = __uint_as_float(sl.y);
        float4 v = emb4[(size_t)sl.x * D4 + lane];
        ax = fmaf(w, v.x, ax); ay = fmaf(w, v.y, ay);
        az = fmaf(w, v.z, az); aw = fmaf(w, v.w, aw);
    }
    size_t o = (size_t)node * D4 + lane;
    bufA[o] = make_ushort4(f_to_bf(ax), f_to_bf(ay), f_to_bf(az), f_to_bf(aw));
    float4 e0 = emb4[o];
    ((float4*)acc)[o] = make_float4(e0.x + ax, e0.y + ay, e0.z + az, e0.w + aw);
}

// ---- Layers 2-3: bf16 gather; optional bf16 dst write; acc += result ----
__global__ void propagateN(const unsigned* __restrict__ row_ptr, const uint2* __restrict__ slots,
                           const ushort4* __restrict__ cur, ushort4* __restrict__ dst_bf,
                           float* __restrict__ acc, int write_dst) {
    int node = blockIdx.x * 16 + (threadIdx.x >> 4);
    int lane = threadIdx.x & 15;
    if (node >= N_NODES) return;
    unsigned beg = row_ptr[node], end = row_ptr[node + 1];
    float ax = 0.f, ay = 0.f, az = 0.f, aw = 0.f;
    for (unsigned k = beg; k < end; ++k) {
        uint2 sl = slots[k];
        float w = __uint_as_float(sl.y);
        float4 v = bf4_to_f4(cur[(size_t)sl.x * D4 + lane]);
        ax = fmaf(w, v.x, ax); ay = fmaf(w, v.y, ay);
        az = fmaf(w, v.z, az); aw = fmaf(w, v.w, aw);
    }
    size_t o = (size_t)node * D4 + lane;
    if (write_dst) dst_bf[o] = make_ushort4(f_to_bf(ax), f_to_bf(ay), f_to_bf(az), f_to_bf(aw));
    float4 c = ((float4*)acc)[o];
    c.x += ax; c.y += ay; c.z += az; c.w += aw;
    ((float4*)acc)[o] = c;
}

// ---- out_emb = emb (region hosted bufB until now); acc *= 0.25 ----
__global__ void finalize(const float4* __restrict__ emb4, float4* __restrict__ out_emb4,
                         float4* __restrict__ acc4) {
    int i = blockIdx.x * blockDim.x + threadIdx.x;
    if (i >= N_NODES * D4) return;
    out_emb4[i] = emb4[i];
    float4 v = acc4[i];
    v.x *= 0.25f; v.y *= 0.25f; v.z *= 0.25f; v.w *= 0.25f;
    acc4[i] = v;
}

extern "C" void kernel_launch(void* const* d_in, const int* in_sizes, int n_in,
                              void* d_out, int out_size, void* d_ws, size_t ws_size,
                              hipStream_t stream) {
    const float* emb = (const float*)d_in[0];
    const int* ei = (const int*)d_in[1];
    const float* attr = (const float*)d_in[2];

    float* out_emb = (float*)d_out;          // hosts bufB (bf16) during layers 2-3
    float* out_acc = out_emb + (size_t)N_NODES * 64;
    ushort4* bufB = (ushort4*)out_emb;

    char* ws = (char*)d_ws;
    size_t off = 0;
    auto alloc = [&](size_t bytes) -> void* {
        void* p = ws + off;
        off += (bytes + 255) & ~(size_t)255;
        return p;
    };
    unsigned* cnt_t   = (unsigned*)alloc((size_t)NBK * 4);
    unsigned* cnt_f   = (unsigned*)alloc((size_t)NBK * 4);
    size_t zero_bytes = off;
    unsigned* base_t  = (unsigned*)alloc((size_t)(NBK + 1) * 4);
    unsigned* base_f  = (unsigned*)alloc((size_t)(NBK + 1) * 4);
    unsigned* pos_t   = (unsigned*)alloc((size_t)NBK * 4);
    unsigned* pos_f   = (unsigned*)alloc((size_t)NBK * 4);
    unsigned* row_ptr = (unsigned*)alloc((size_t)(N_NODES + 1) * 4);
    float* s_from_inv = (float*)   alloc((size_t)N_NODES * 4);
    uint2* bt         = (uint2*)   alloc((size_t)N_EDGES * 8);
    uint2* bf         = (uint2*)   alloc((size_t)N_EDGES * 8);
    uint2* slots      = bf;        // bf fully consumed by bucket_sum_f before slots written
    ushort4* bufA     = (ushort4*) alloc((size_t)N_NODES * 64 * 2);
    (void)ws_size;

    hipMemsetAsync(d_ws, 0, zero_bytes, stream);

    hist_kernel<<<256, 256, 0, stream>>>(ei, cnt_t, cnt_f);
    scan_buckets<<<1, 512, 0, stream>>>(cnt_t, cnt_f, base_t, base_f, pos_t, pos_f);
    const int pblocks = (N_EDGES + PTILE - 1) / PTILE;
    partition<<<pblocks, 256, 0, stream>>>(ei, attr, pos_t, pos_f, bt, bf);
    bucket_sum_f<<<NBK, 256, 0, stream>>>(base_f, bf, s_from_inv);
    bucket_csr_t<<<NBK, 256, 0, stream>>>(base_t, bt, s_from_inv, row_ptr, slots);

    const int pgrid = (N_NODES * 16 + 255) / 256;
    propagate1<<<pgrid, 256, 0, stream>>>(row_ptr, slots, emb, bufA, out_acc);
    propagateN<<<pgrid, 256, 0, stream>>>(row_ptr, slots, bufA, bufB, out_acc, 1);
    propagateN<<<pgrid, 256, 0, stream>>>(row_ptr, slots, bufB, nullptr, out_acc, 0);

    const int vgrid = (N_NODES * D4 + 255) / 256;
    finalize<<<vgrid, 256, 0, stream>>>((const float4*)emb, (float4*)out_emb, (float4*)out_acc);
}